// Round 1
// baseline (83.141 us; speedup 1.0000x reference)
//
#include <hip/hip_runtime.h>

#define OUT_CH 128
#define WAVES_PER_BLOCK 4

// Single fused kernel: one wave per edge.
//
// Phase 1 — boundary find: cooperative 32-ary lower_bound over the sorted
// segment_ids. Lanes 0-31 search target e, lanes 32-63 search target e+1.
// Each round: 32 probes per group + one __ballot → range shrinks 32x, so
// T = 2^21 resolves in 5 rounds (~5 dependent cached loads, vs a full
// 8.4 MB streaming pass + kernel launch in the old 2-kernel version).
// Round-1 probe addresses are range-dependent only (identical across all
// waves) → pure L2 broadcast.
//
// Phase 2 — histogram: int4 token loads (aligned-down base, per-element
// range guards), packed 4x16-bit counts in one u64 (max seg len ~350 <<
// 65535), 6-step 64-lane butterfly, then each lane emits 2 channels:
// out[e] = (counts . emb) / max(total, 1).
//
// d_ws is untouched (no dependence on poisoned contents by construction).
__global__ __launch_bounds__(WAVES_PER_BLOCK * 64)
void edge_fused_kernel(const int* __restrict__ tokens,
                       const int* __restrict__ segids,
                       const float* __restrict__ emb,
                       float* __restrict__ out,
                       int T, int E) {
    const int lane = threadIdx.x & 63;
    const int wid  = threadIdx.x >> 6;
    const int e = blockIdx.x * WAVES_PER_BLOCK + wid;
    if (e >= E) return;

    // ---- Phase 1: cooperative lower_bound for targets e and e+1 ----
    const int grp    = lane >> 5;    // 0: target e, 1: target e+1
    const int sub    = lane & 31;
    const int target = e + grp;

    // Invariant: lower_bound(target) in [lo, hi].
    int lo = 0, hi = T;
    while (hi > lo) {
        const int len = hi - lo;                       // <= 2^21
        // 32 monotone probe positions; pos(31) == hi. (sub+1)*len <= 2^26, no overflow.
        const int pos = lo + (((sub + 1) * len) >> 5);
        const bool c = (pos >= T) || (segids[pos] >= target);  // monotone in sub; c(31) always true
        const unsigned long long bal = __ballot(c);
        const unsigned int gm = (unsigned int)(bal >> (grp << 5));
        const int f = __ffs(gm) - 1;                   // first true lane within group, in [0,31]
        // lb in (pos(f-1), pos(f)]  (f>0: seg[pos(f-1)] < target), or [lo, pos(0)] (f==0)
        const int nhi = lo + (((f + 1) * len) >> 5);
        const int nlo = (f == 0) ? lo : (lo + ((f * len) >> 5) + 1);
        hi = nhi;
        lo = nlo;
    }
    const int start = __shfl(lo, 0, 64);
    const int end   = __shfl(lo, 32, 64);

    // ---- Phase 2: packed register histogram over [start, end) ----
    unsigned long long acc = 0;
    const int base = start & ~3;     // 16B-aligned int4 base; T % 4 == 0 keeps loads in-bounds
    for (int k = base + (lane << 2); k < end; k += WAVES_PER_BLOCK * 64) {
        const int4 t4 = *(const int4*)(tokens + k);
        if (k >= start && k + 3 < end) {               // whole quad in range (common case)
            acc += 1ull << (t4.x << 4);
            acc += 1ull << (t4.y << 4);
            acc += 1ull << (t4.z << 4);
            acc += 1ull << (t4.w << 4);
        } else {                                       // ragged head/tail
            if (k + 0 >= start && k + 0 < end) acc += 1ull << (t4.x << 4);
            if (k + 1 >= start && k + 1 < end) acc += 1ull << (t4.y << 4);
            if (k + 2 >= start && k + 2 < end) acc += 1ull << (t4.z << 4);
            if (k + 3 >= start && k + 3 < end) acc += 1ull << (t4.w << 4);
        }
    }
#pragma unroll
    for (int m = 32; m > 0; m >>= 1) {
        acc += __shfl_xor(acc, m, 64);
    }

    const float c0 = (float)(acc & 0xFFFFull);
    const float c1 = (float)((acc >> 16) & 0xFFFFull);
    const float c2 = (float)((acc >> 32) & 0xFFFFull);
    const float c3 = (float)((acc >> 48) & 0xFFFFull);
    const float tot = c0 + c1 + c2 + c3;
    const float inv = 1.0f / fmaxf(tot, 1.0f);

    const int c = lane << 1;
    const float2 e0 = *(const float2*)(emb + 0 * OUT_CH + c);
    const float2 e1 = *(const float2*)(emb + 1 * OUT_CH + c);
    const float2 e2 = *(const float2*)(emb + 2 * OUT_CH + c);
    const float2 e3 = *(const float2*)(emb + 3 * OUT_CH + c);

    float2 r;
    r.x = (c0 * e0.x + c1 * e1.x + c2 * e2.x + c3 * e3.x) * inv;
    r.y = (c0 * e0.y + c1 * e1.y + c2 * e2.y + c3 * e3.y) * inv;
    *(float2*)(out + (size_t)e * OUT_CH + c) = r;
}

extern "C" void kernel_launch(void* const* d_in, const int* in_sizes, int n_in,
                              void* d_out, int out_size, void* d_ws, size_t ws_size,
                              hipStream_t stream) {
    // inputs (setup_inputs order):
    // 0: overlap_similarity f32 [E]   (unused)
    // 1: overlap_length     f32 [E]   (unused)
    // 2: tokens             i32 [T]
    // 3: segment_ids        i32 [T]   (sorted)
    // 4: embedding          f32 [4,128]
    // 5: n_edges            i32 [1]   (device scalar; derive E from out_size)
    const int* tokens = (const int*)d_in[2];
    const int* segids = (const int*)d_in[3];
    const float* emb  = (const float*)d_in[4];
    float* out = (float*)d_out;

    const int T = in_sizes[2];
    const int E = out_size / OUT_CH;

    const int blocks = (E + WAVES_PER_BLOCK - 1) / WAVES_PER_BLOCK;
    edge_fused_kernel<<<blocks, WAVES_PER_BLOCK * 64, 0, stream>>>(
        tokens, segids, emb, out, T, E);
}

// Round 2
// 82.999 us; speedup vs baseline: 1.0017x; 1.0017x over previous
//
#include <hip/hip_runtime.h>

#define OUT_CH 128
#define WAVES_PER_BLOCK 4

// Single fused kernel: one wave per edge.
//
// Phase 1 — boundary find: cooperative 32-ary lower_bound over the sorted
// segment_ids. Lanes 0-31 search target e, lanes 32-63 search target e+1.
// Round 1 is INTERPOLATION-GUIDED: segids are uniform-random over [0,E), so
// lower_bound(t) ~ t*(T/E) = t<<8 with sigma = sqrt(T/4) = 724. 32 probes at
// stride 384 centered on the guess cover +-6144 (~8.5 sigma) and collapse the
// range 2^21 -> <=384 in one round; uniform 32-ary rounds finish in 3 more
// (384 -> 12 -> 1 -> 0). Lane 31's probe is pinned to hi, so the invariant
// "lb in [lo,hi]" is preserved even if the guess window misses (the loop then
// falls back to uniform rounds over the escaped range — correct, just slower,
// probability ~0).
//
// Phase 2 — histogram: int4 token loads (aligned-down base, per-element
// range guards), packed 4x16-bit counts in one u64 (max seg len ~350 <<
// 65535), 6-step 64-lane butterfly, then each lane emits 2 channels:
// out[e] = (counts . emb) / max(total, 1).
//
// d_ws is untouched (no dependence on poisoned contents by construction).
__global__ __launch_bounds__(WAVES_PER_BLOCK * 64)
void edge_fused_kernel(const int* __restrict__ tokens,
                       const int* __restrict__ segids,
                       const float* __restrict__ emb,
                       float* __restrict__ out,
                       int T, int E) {
    const int lane = threadIdx.x & 63;
    const int wid  = threadIdx.x >> 6;
    const int e = blockIdx.x * WAVES_PER_BLOCK + wid;
    if (e >= E) return;

    // ---- Phase 1: cooperative lower_bound for targets e and e+1 ----
    const int grp    = lane >> 5;    // 0: target e, 1: target e+1
    const int sub    = lane & 31;
    const int target = e + grp;

    // Invariant: lower_bound(target) in [lo, hi].
    int lo = 0, hi = T;

    // Round 1: interpolation-guided probes. cond(p) := (p>=T)||(segids[p]>=target)
    // is a monotone step: true iff p >= lb. Probes are monotone in sub with
    // p(31)=hi, so f = first-true exists and lb in (p(f-1), p(f)].
    {
        const int g = target << 8;   // E[lb] = target * (T/E) = target*256
        const auto pof = [&](int s) -> int {
            if (s >= 31) return T;                 // pinned: cond(T) true
            int q = g + ((s - 16) * 384);          // g-6144 .. g+5760
            q = (q < 0) ? 0 : q;
            return (q > T) ? T : q;
        };
        const int p = pof(sub);
        const bool c = (p >= T) || (segids[p] >= target);
        const unsigned long long bal = __ballot(c);
        const unsigned int gm = (unsigned int)(bal >> (grp << 5));
        const int f = __ffs(gm) - 1;               // in [0,31]
        hi = pof(f);
        lo = (f == 0) ? lo : (pof(f - 1) + 1);
    }

    // Uniform 32-ary rounds (typically 3: 384 -> 12 -> 1 -> 0).
    while (hi > lo) {
        const int len = hi - lo;                       // <= 2^21
        const int pos = lo + (((sub + 1) * len) >> 5); // monotone; pos(31)==hi
        const bool c = (pos >= T) || (segids[pos] >= target);
        const unsigned long long bal = __ballot(c);
        const unsigned int gm = (unsigned int)(bal >> (grp << 5));
        const int f = __ffs(gm) - 1;
        const int nhi = lo + (((f + 1) * len) >> 5);
        const int nlo = (f == 0) ? lo : (lo + ((f * len) >> 5) + 1);
        hi = nhi;
        lo = nlo;
    }
    const int start = __shfl(lo, 0, 64);
    const int end   = __shfl(lo, 32, 64);

    // ---- Phase 2: packed register histogram over [start, end) ----
    unsigned long long acc = 0;
    const int base = start & ~3;     // 16B-aligned int4 base; T % 4 == 0 keeps loads in-bounds
    for (int k = base + (lane << 2); k < end; k += 64 * 4) {
        const int4 t4 = *(const int4*)(tokens + k);
        if (k >= start && k + 3 < end) {               // whole quad in range (common case)
            acc += 1ull << (t4.x << 4);
            acc += 1ull << (t4.y << 4);
            acc += 1ull << (t4.z << 4);
            acc += 1ull << (t4.w << 4);
        } else {                                       // ragged head/tail
            if (k + 0 >= start && k + 0 < end) acc += 1ull << (t4.x << 4);
            if (k + 1 >= start && k + 1 < end) acc += 1ull << (t4.y << 4);
            if (k + 2 >= start && k + 2 < end) acc += 1ull << (t4.z << 4);
            if (k + 3 >= start && k + 3 < end) acc += 1ull << (t4.w << 4);
        }
    }
#pragma unroll
    for (int m = 32; m > 0; m >>= 1) {
        acc += __shfl_xor(acc, m, 64);
    }

    const float c0 = (float)(acc & 0xFFFFull);
    const float c1 = (float)((acc >> 16) & 0xFFFFull);
    const float c2 = (float)((acc >> 32) & 0xFFFFull);
    const float c3 = (float)((acc >> 48) & 0xFFFFull);
    const float tot = c0 + c1 + c2 + c3;
    const float inv = 1.0f / fmaxf(tot, 1.0f);

    const int c = lane << 1;
    const float2 e0 = *(const float2*)(emb + 0 * OUT_CH + c);
    const float2 e1 = *(const float2*)(emb + 1 * OUT_CH + c);
    const float2 e2 = *(const float2*)(emb + 2 * OUT_CH + c);
    const float2 e3 = *(const float2*)(emb + 3 * OUT_CH + c);

    float2 r;
    r.x = (c0 * e0.x + c1 * e1.x + c2 * e2.x + c3 * e3.x) * inv;
    r.y = (c0 * e0.y + c1 * e1.y + c2 * e2.y + c3 * e3.y) * inv;
    *(float2*)(out + (size_t)e * OUT_CH + c) = r;
}

extern "C" void kernel_launch(void* const* d_in, const int* in_sizes, int n_in,
                              void* d_out, int out_size, void* d_ws, size_t ws_size,
                              hipStream_t stream) {
    // inputs (setup_inputs order):
    // 0: overlap_similarity f32 [E]   (unused)
    // 1: overlap_length     f32 [E]   (unused)
    // 2: tokens             i32 [T]
    // 3: segment_ids        i32 [T]   (sorted)
    // 4: embedding          f32 [4,128]
    // 5: n_edges            i32 [1]   (device scalar; derive E from out_size)
    const int* tokens = (const int*)d_in[2];
    const int* segids = (const int*)d_in[3];
    const float* emb  = (const float*)d_in[4];
    float* out = (float*)d_out;

    const int T = in_sizes[2];
    const int E = out_size / OUT_CH;

    const int blocks = (E + WAVES_PER_BLOCK - 1) / WAVES_PER_BLOCK;
    edge_fused_kernel<<<blocks, WAVES_PER_BLOCK * 64, 0, stream>>>(
        tokens, segids, emb, out, T, E);
}